// Round 7
// baseline (436.437 us; speedup 1.0000x reference)
//
#include <hip/hip_runtime.h>

// Problem: B,H,W,D = 64,32,32,64 ; K=1024 ; N = 65536
#define NPTS   65536
#define DDIM   64
#define KCODES 1024
#define QOUT_ELEMS (NPTS * DDIM)

typedef _Float16 half8    __attribute__((ext_vector_type(8)));
typedef float    floatx16 __attribute__((ext_vector_type(16)));
typedef unsigned int uint;

#define AS1 __attribute__((address_space(1)))
#define AS3 __attribute__((address_space(3)))

// ws: ehp [0,128K) chunk-major f16 | elp [128K,256K) | e2 fp32 [256K,260K)
// diag scratch: [1MiB, 3MiB) in 512KB regions per variant
#define WS_EHP   0
#define WS_ELP   (128*1024)
#define WS_E2    (256*1024)

static __device__ __forceinline__ void gl_lds16(const void* g, void* l) {
    __builtin_amdgcn_global_load_lds((const AS1 uint*)g, (AS3 uint*)l, 16, 0, 0);
}

// ---------------------------------------------------------------------------
// Prep (unchanged): fp16 hi/lo split, chunk-major tiles; e2 fp32.
// ---------------------------------------------------------------------------
__global__ void eprep_kernel(const float* __restrict__ emb, char* __restrict__ ws) {
    const int tid = threadIdx.x;
    const int w = tid >> 6, d = tid & 63;
    const int k = blockIdx.x * 4 + w;
    float v = emb[(size_t)k * DDIM + d];
    _Float16 h = (_Float16)v;
    _Float16 l = (_Float16)(v - (float)h);
    size_t off = (size_t)(k >> 5) * 4096 + (size_t)(d >> 3) * 512
               + (size_t)(k & 31) * 16 + (size_t)(d & 7) * 2;
    *(_Float16*)(ws + WS_EHP + off) = h;
    *(_Float16*)(ws + WS_ELP + off) = l;
    float s = v * v;
    #pragma unroll
    for (int m = 1; m < 64; m <<= 1) s += __shfl_xor(s, m, 64);
    if (d == 0) ((float*)(ws + WS_E2))[k] = s;
}

#define MFMA(A,B,C) __builtin_amdgcn_mfma_f32_32x32x16_f16(A,B,C,0,0,0)

// ===========================================================================
// DIAGNOSTIC kernel (this round only). V selects the ablation; REPS repeats
// the whole 32-tile pipeline so each dispatch towers over the ~44us fill
// dispatches and lands in the rocprof top-5 table.
//   V0: full R6 pipeline (control)
//   V1: memory-only (STAGE+WAITBAR+READF; MFMA/argmin -> 8-add fold)
//   V2: compute-only (frags loaded once; 32x COMP; no LDS traffic/barriers)
//   V3: full but NO waits/barriers (races OK; scratch discarded)
// Rule#17 discipline: every ablated value feeds the scratch write (no DCE).
// LDS arrays kept allocated in ALL variants (occupancy parity: 2 blocks/CU).
// ===========================================================================
template<int V, int REPS>
__global__ __launch_bounds__(256, 2) void vq_diag(
    const float* __restrict__ z,
    const char* __restrict__ ws_c,
    float* __restrict__ scratch)
{
    const int tid  = threadIdx.x;
    const int lane = tid & 63;
    const int w    = __builtin_amdgcn_readfirstlane(tid >> 6);
    const int col  = lane & 31;
    const int sel8 = lane >> 5;
    const int pgrp = blockIdx.x;

    __shared__ char  ebuf[4][8192];
    __shared__ float lds_e2[1024];

    const int pt = pgrp * 128 + w * 32 + col;
    half8 ah[4], al[4];
    {
        const float* zrow = z + (size_t)pt * DDIM + sel8 * 8;
        #pragma unroll
        for (int ks = 0; ks < 4; ++ks) {
            float4 u0 = *(const float4*)(zrow + ks * 16);
            float4 u1 = *(const float4*)(zrow + ks * 16 + 4);
            float tv[8] = {u0.x, u0.y, u0.z, u0.w, u1.x, u1.y, u1.z, u1.w};
            #pragma unroll
            for (int j = 0; j < 8; ++j) {
                float a = -2.0f * tv[j];
                _Float16 hh = (_Float16)a;
                ah[ks][j] = hh;
                al[ks][j] = (_Float16)(a - (float)hh);
            }
        }
    }
    asm volatile("s_waitcnt vmcnt(0)" ::: "memory");
    __builtin_amdgcn_sched_barrier(0);

    const floatx16 zeroC = {};
    float best[16];
    int   bt[16];
    #pragma unroll
    for (int r = 0; r < 16; ++r) { best[r] = 3.4e38f; bt[r] = 0; }

    const int opnd = w >> 1, hsel = w & 1;
    const char* gsrc = ws_c + (opnd ? WS_ELP : WS_EHP) + hsel * 2048 + lane * 16;
    char* lbase = &ebuf[0][0] + opnd * 4096 + hsel * 2048;
    const int myoff = sel8 * 512 + col * 16;
    float fs = 0.0f;   // V1 fold accumulator

#define STAGE(BUF, T) do {                                                    \
    const char* _s = gsrc + (size_t)(T) * 4096;                               \
    char* _d = lbase + (BUF) * 8192;                                          \
    gl_lds16(_s,        _d);                                                  \
    gl_lds16(_s + 1024, _d + 1024);                                           \
} while (0)

#define READF(BUF, T, BH, BL, E2) do {                                        \
    const char* _b = &ebuf[BUF][0] + myoff;                                   \
    _Pragma("unroll")                                                         \
    for (int ks = 0; ks < 4; ++ks) {                                          \
        BH[ks] = *(const half8*)(_b + ks * 1024);                             \
        BL[ks] = *(const half8*)(_b + 4096 + ks * 1024);                      \
    }                                                                         \
    E2 = lds_e2[(T) * 32 + col];                                              \
} while (0)

#define DOT(T, BH, BL, E2) do {                                               \
    if constexpr (V == 1) {                                                   \
        fs += (float)BH[0][0] + (float)BH[1][0] + (float)BH[2][0]             \
            + (float)BH[3][0] + (float)BL[0][0] + (float)BL[1][0]             \
            + (float)BL[2][0] + (float)BL[3][0] + (E2);                       \
    } else {                                                                  \
        __builtin_amdgcn_s_setprio(1);                                        \
        floatx16 c0 = MFMA(ah[0], BH[0], zeroC);                              \
        floatx16 c1 = MFMA(ah[0], BL[0], zeroC);                              \
        c0 = MFMA(ah[1], BH[1], c0);  c1 = MFMA(ah[1], BL[1], c1);            \
        c0 = MFMA(ah[2], BH[2], c0);  c1 = MFMA(ah[2], BL[2], c1);            \
        c0 = MFMA(ah[3], BH[3], c0);  c1 = MFMA(ah[3], BL[3], c1);            \
        c0 = MFMA(al[0], BH[0], c0);  c1 = MFMA(al[2], BH[2], c1);            \
        c0 = MFMA(al[1], BH[1], c0);  c1 = MFMA(al[3], BH[3], c1);            \
        __builtin_amdgcn_s_setprio(0);                                        \
        _Pragma("unroll")                                                     \
        for (int r = 0; r < 16; ++r) {                                        \
            float d = (c0[r] + c1[r]) + (E2);                                 \
            bool c = d < best[r];                                             \
            best[r] = c ? d   : best[r];                                      \
            bt[r]   = c ? (T) : bt[r];                                        \
        }                                                                     \
    }                                                                         \
} while (0)

#define WAITBAR(N) do {                                                      \
    if constexpr (V != 3) {                                                  \
        asm volatile("s_waitcnt vmcnt(" #N ") lgkmcnt(0)" ::: "memory");     \
        __builtin_amdgcn_sched_barrier(0);                                   \
        __builtin_amdgcn_s_barrier();                                        \
        __builtin_amdgcn_sched_barrier(0);                                   \
    }                                                                        \
} while (0)

    half8 bhA[4], blA[4], bhB[4], blB[4];
    float e2A, e2B;

    if constexpr (V == 2) {
        // compute-only: one-time direct frag load, then pure COMP loop
        const char* _b = ws_c + myoff;
        #pragma unroll
        for (int ks = 0; ks < 4; ++ks) {
            bhA[ks] = *(const half8*)(_b + ks * 1024);
            blA[ks] = *(const half8*)(_b + WS_ELP + ks * 1024);
        }
        e2A = ((const float*)(ws_c + WS_E2))[col];
        #pragma unroll 1
        for (int rep = 0; rep < REPS; ++rep) {
            #pragma unroll 1
            for (int t = 0; t < 32; ++t) DOT(t, bhA, blA, e2A);
        }
    } else {
        #pragma unroll 1
        for (int rep = 0; rep < REPS; ++rep) {
            gl_lds16(ws_c + WS_E2 + w * 1024 + lane * 16,
                     (char*)lds_e2 + w * 1024);
            STAGE(0, 0);
            STAGE(1, 1);
            STAGE(2, 2);
            WAITBAR(4);
            READF(0, 0, bhA, blA, e2A);
            STAGE(3, 3);

            #pragma unroll 1
            for (int t = 0; t < 28; t += 2) {
                WAITBAR(4);
                READF((t + 1) & 3, t + 1, bhB, blB, e2B);
                STAGE((t + 4) & 3, t + 4);
                DOT(t, bhA, blA, e2A);

                WAITBAR(4);
                READF((t + 2) & 3, t + 2, bhA, blA, e2A);
                STAGE((t + 5) & 3, t + 5);
                DOT(t + 1, bhB, blB, e2B);
            }
            WAITBAR(4);
            READF(29 & 3, 29, bhB, blB, e2B);
            DOT(28, bhA, blA, e2A);
            WAITBAR(2);
            READF(30 & 3, 30, bhA, blA, e2A);
            DOT(29, bhB, blB, e2B);
            WAITBAR(0);
            READF(31 & 3, 31, bhB, blB, e2B);
            DOT(30, bhA, blA, e2A);
            DOT(31, bhB, blB, e2B);
        }
    }
#undef STAGE
#undef READF
#undef DOT
#undef WAITBAR

    // epilogue: butterfly (same VALU as real) + sink EVERYTHING to scratch
    int code[16];
    #pragma unroll
    for (int r = 0; r < 16; ++r) code[r] = bt[r] * 32 + col;
    #pragma unroll
    for (int m = 1; m < 32; m <<= 1) {
        #pragma unroll
        for (int r = 0; r < 16; ++r) {
            float ov = __shfl_xor(best[r], m, 64);
            int   oc = __shfl_xor(code[r], m, 64);
            bool c = (ov < best[r]) || (ov == best[r] && oc < code[r]);
            best[r] = c ? ov : best[r];
            code[r] = c ? oc : code[r];
        }
    }
    float accv = fs;
    #pragma unroll
    for (int r = 0; r < 16; ++r) accv += best[r] + (float)code[r];
    scratch[pgrp * 256 + tid] = accv;
    if (pgrp == 0x7fffffff)   // never true: keeps LDS allocated in V2
        scratch[0] = (float)ebuf[0][0] + lds_e2[0];
}

// ===========================================================================
// REAL kernel: byte-identical to Round-6 (best verified, ~40us, absmax 0).
// ===========================================================================
__global__ __launch_bounds__(256, 2) void vq_kernel(
    const float* __restrict__ z,
    const char* __restrict__ ws_c,
    const float* __restrict__ emb,
    float* __restrict__ out)
{
    const int tid  = threadIdx.x;
    const int lane = tid & 63;
    const int w    = __builtin_amdgcn_readfirstlane(tid >> 6);
    const int col  = lane & 31;
    const int sel8 = lane >> 5;
    const int pgrp = blockIdx.x;

    __shared__ char  ebuf[4][8192];
    __shared__ float lds_e2[1024];
    __shared__ int   s_final[128];

    const int pt = pgrp * 128 + w * 32 + col;
    half8 ah[4], al[4];
    {
        const float* zrow = z + (size_t)pt * DDIM + sel8 * 8;
        #pragma unroll
        for (int ks = 0; ks < 4; ++ks) {
            float4 u0 = *(const float4*)(zrow + ks * 16);
            float4 u1 = *(const float4*)(zrow + ks * 16 + 4);
            float tv[8] = {u0.x, u0.y, u0.z, u0.w, u1.x, u1.y, u1.z, u1.w};
            #pragma unroll
            for (int j = 0; j < 8; ++j) {
                float a = -2.0f * tv[j];
                _Float16 hh = (_Float16)a;
                ah[ks][j] = hh;
                al[ks][j] = (_Float16)(a - (float)hh);
            }
        }
    }
    asm volatile("s_waitcnt vmcnt(0)" ::: "memory");
    __builtin_amdgcn_sched_barrier(0);

    const floatx16 zeroC = {};
    float best[16];
    int   bt[16];
    #pragma unroll
    for (int r = 0; r < 16; ++r) { best[r] = 3.4e38f; bt[r] = 0; }

    const int opnd = w >> 1, hsel = w & 1;
    const char* gsrc = ws_c + (opnd ? WS_ELP : WS_EHP) + hsel * 2048 + lane * 16;
    char* lbase = &ebuf[0][0] + opnd * 4096 + hsel * 2048;

#define STAGE(BUF, T) do {                                                    \
    const char* _s = gsrc + (size_t)(T) * 4096;                               \
    char* _d = lbase + (BUF) * 8192;                                          \
    gl_lds16(_s,        _d);                                                  \
    gl_lds16(_s + 1024, _d + 1024);                                           \
} while (0)

    const int myoff = sel8 * 512 + col * 16;

#define READF(BUF, T, BH, BL, E2) do {                                        \
    const char* _b = &ebuf[BUF][0] + myoff;                                   \
    _Pragma("unroll")                                                         \
    for (int ks = 0; ks < 4; ++ks) {                                          \
        BH[ks] = *(const half8*)(_b + ks * 1024);                             \
        BL[ks] = *(const half8*)(_b + 4096 + ks * 1024);                      \
    }                                                                         \
    E2 = lds_e2[(T) * 32 + col];                                              \
} while (0)

#define COMP(T, BH, BL, E2) do {                                              \
    __builtin_amdgcn_s_setprio(1);                                            \
    floatx16 c0 = MFMA(ah[0], BH[0], zeroC);                                  \
    floatx16 c1 = MFMA(ah[0], BL[0], zeroC);                                  \
    c0 = MFMA(ah[1], BH[1], c0);  c1 = MFMA(ah[1], BL[1], c1);                \
    c0 = MFMA(ah[2], BH[2], c0);  c1 = MFMA(ah[2], BL[2], c1);                \
    c0 = MFMA(ah[3], BH[3], c0);  c1 = MFMA(ah[3], BL[3], c1);                \
    c0 = MFMA(al[0], BH[0], c0);  c1 = MFMA(al[2], BH[2], c1);                \
    c0 = MFMA(al[1], BH[1], c0);  c1 = MFMA(al[3], BH[3], c1);                \
    __builtin_amdgcn_s_setprio(0);                                            \
    _Pragma("unroll")                                                         \
    for (int r = 0; r < 16; ++r) {                                            \
        float d = (c0[r] + c1[r]) + (E2);                                     \
        bool c = d < best[r];                                                 \
        best[r] = c ? d   : best[r];                                          \
        bt[r]   = c ? (T) : bt[r];                                            \
    }                                                                         \
} while (0)

#define WAITBAR(N) do {                                                       \
    asm volatile("s_waitcnt vmcnt(" #N ") lgkmcnt(0)" ::: "memory");          \
    __builtin_amdgcn_sched_barrier(0);                                        \
    __builtin_amdgcn_s_barrier();                                             \
    __builtin_amdgcn_sched_barrier(0);                                        \
} while (0)

    half8 bhA[4], blA[4], bhB[4], blB[4];
    float e2A, e2B;

    gl_lds16(ws_c + WS_E2 + w * 1024 + lane * 16, (char*)lds_e2 + w * 1024);
    STAGE(0, 0);
    STAGE(1, 1);
    STAGE(2, 2);
    WAITBAR(4);
    READF(0, 0, bhA, blA, e2A);
    STAGE(3, 3);

    #pragma unroll 1
    for (int t = 0; t < 28; t += 2) {
        WAITBAR(4);
        READF((t + 1) & 3, t + 1, bhB, blB, e2B);
        STAGE((t + 4) & 3, t + 4);
        COMP(t, bhA, blA, e2A);

        WAITBAR(4);
        READF((t + 2) & 3, t + 2, bhA, blA, e2A);
        STAGE((t + 5) & 3, t + 5);
        COMP(t + 1, bhB, blB, e2B);
    }

    WAITBAR(4);
    READF(29 & 3, 29, bhB, blB, e2B);
    COMP(28, bhA, blA, e2A);
    WAITBAR(2);
    READF(30 & 3, 30, bhA, blA, e2A);
    COMP(29, bhB, blB, e2B);
    WAITBAR(0);
    READF(31 & 3, 31, bhB, blB, e2B);
    COMP(30, bhA, blA, e2A);
    COMP(31, bhB, blB, e2B);
#undef STAGE
#undef READF
#undef COMP
#undef WAITBAR

    int code[16];
    #pragma unroll
    for (int r = 0; r < 16; ++r) code[r] = bt[r] * 32 + col;
    #pragma unroll
    for (int m = 1; m < 32; m <<= 1) {
        #pragma unroll
        for (int r = 0; r < 16; ++r) {
            float ov = __shfl_xor(best[r], m, 64);
            int   oc = __shfl_xor(code[r], m, 64);
            bool c = (ov < best[r]) || (ov == best[r] && oc < code[r]);
            best[r] = c ? ov : best[r];
            code[r] = c ? oc : code[r];
        }
    }
    if (col == 0) {
        #pragma unroll
        for (int r = 0; r < 16; ++r) {
            int row = (r & 3) + 8 * (r >> 2) + 4 * sel8;
            s_final[w * 32 + row] = code[r];
        }
    }
    __syncthreads();

    if (tid < 128)
        out[QOUT_ELEMS + (size_t)pgrp * 128 + tid] = (float)s_final[tid];
    float4* outq = (float4*)out;
    const float4* emb4 = (const float4*)emb;
    #pragma unroll
    for (int it = 0; it < 8; ++it) {
        int f  = it * 256 + tid;
        int p  = f >> 4;
        int d4 = f & 15;
        int ks = s_final[p];
        outq[((size_t)pgrp * 128 + p) * (DDIM / 4) + d4] =
            emb4[(size_t)ks * (DDIM / 4) + d4];
    }
}

extern "C" void kernel_launch(void* const* d_in, const int* in_sizes, int n_in,
                              void* d_out, int out_size, void* d_ws, size_t ws_size,
                              hipStream_t stream) {
    const float* z   = (const float*)d_in[0];
    const float* emb = (const float*)d_in[1];
    float* out = (float*)d_out;
    char* ws = (char*)d_ws;

    eprep_kernel<<<KCODES / 4, 256, 0, stream>>>(emb, ws);

    // diagnostics (this round only): each writes its own 512KB scratch region
    float* sc0 = (float*)(ws + (1 << 20) + 0 * (512 << 10));
    float* sc1 = (float*)(ws + (1 << 20) + 1 * (512 << 10));
    float* sc2 = (float*)(ws + (1 << 20) + 2 * (512 << 10));
    float* sc3 = (float*)(ws + (1 << 20) + 3 * (512 << 10));
    vq_diag<0, 4><<<NPTS / 128, 256, 0, stream>>>(z, ws, sc0);
    vq_diag<1, 4><<<NPTS / 128, 256, 0, stream>>>(z, ws, sc1);
    vq_diag<2, 4><<<NPTS / 128, 256, 0, stream>>>(z, ws, sc2);
    vq_diag<3, 4><<<NPTS / 128, 256, 0, stream>>>(z, ws, sc3);

    // real kernel (unchanged Round-6 best)
    vq_kernel<<<NPTS / 128, 256, 0, stream>>>(z, ws, emb, out);
}

// Round 8
// 135.797 us; speedup vs baseline: 3.2139x; 3.2139x over previous
//
#include <hip/hip_runtime.h>

// Problem: B,H,W,D = 64,32,32,64 ; K=1024 ; N = 65536
#define NPTS   65536
#define DDIM   64
#define KCODES 1024
#define QOUT_ELEMS (NPTS * DDIM)

typedef _Float16 half8    __attribute__((ext_vector_type(8)));
typedef float    floatx16 __attribute__((ext_vector_type(16)));
typedef unsigned int uint;

#define AS1 __attribute__((address_space(1)))
#define AS3 __attribute__((address_space(3)))

// ws: ehp [0,128K) chunk-major f16 | elp [128K,256K) | e2 fp32 [256K,260K)
#define WS_EHP   0
#define WS_ELP   (128*1024)
#define WS_E2    (256*1024)

static __device__ __forceinline__ void gl_lds16(const void* g, void* l) {
    __builtin_amdgcn_global_load_lds((const AS1 uint*)g, (AS3 uint*)l, 16, 0, 0);
}

// ---------------------------------------------------------------------------
// Prep: one wave per code. fp16 hi/lo split, CHUNK-MAJOR tiles:
// tile T=k>>5, chunk j=d>>3, code-in-tile c=k&31:
//   byte off = T*4096 + j*512 + c*16 + (d&7)*2
// e2 (||e||^2) stored as plain fp32 (added post-MFMA, exact).
// ---------------------------------------------------------------------------
__global__ void eprep_kernel(const float* __restrict__ emb, char* __restrict__ ws) {
    const int tid = threadIdx.x;
    const int w = tid >> 6, d = tid & 63;
    const int k = blockIdx.x * 4 + w;
    float v = emb[(size_t)k * DDIM + d];
    _Float16 h = (_Float16)v;
    _Float16 l = (_Float16)(v - (float)h);
    size_t off = (size_t)(k >> 5) * 4096 + (size_t)(d >> 3) * 512
               + (size_t)(k & 31) * 16 + (size_t)(d & 7) * 2;
    *(_Float16*)(ws + WS_EHP + off) = h;
    *(_Float16*)(ws + WS_ELP + off) = l;
    float s = v * v;
    #pragma unroll
    for (int m = 1; m < 64; m <<= 1) s += __shfl_xor(s, m, 64);
    if (d == 0) ((float*)(ws + WS_E2))[k] = s;
}

// ---------------------------------------------------------------------------
// Main: grid 512, block 256 = 4 waves; wave w owns 32 points (pgrp*128+w*32+col)
// over the FULL K=1024 (32 tiles). R6 deep-ring structure (4-deep LDS ring,
// counted vmcnt, raw s_barrier, READF one tile ahead).
//
// Round-8 change: FOUR independent 3-deep MFMA chains (was two 6-deep).
// Evidence (R7 ablation): sync-free warm pipeline (V3) still takes 1125
// cy/wave-tile vs 384 cy of matrix-pipe work -> wave-serial chain latency
// (~150cy per dependent 32x32 MFMA; 6-deep = ~900cy) is the wall, with only
// ~2 waves/SIMD to fill the gaps. Halving depth to 3 should cut the serial
// path to ~650cy/tile. Cost: +32 VGPR (two more f32x16 accs).
//
// MFMA 32x32x16 f16 layouts (verified, absmax 0):
//   A[m][k]: m=lane&31, k=(lane>>5)*8+j ; B same with n=lane&31 ;
//   C/D: col=lane&31, row=(r&3)+8*(r>>2)+4*(lane>>5)
// ---------------------------------------------------------------------------
#define MFMA(A,B,C) __builtin_amdgcn_mfma_f32_32x32x16_f16(A,B,C,0,0,0)

__global__ __launch_bounds__(256, 2) void vq_kernel(
    const float* __restrict__ z,
    const char* __restrict__ ws_c,
    const float* __restrict__ emb,
    float* __restrict__ out)
{
    const int tid  = threadIdx.x;
    const int lane = tid & 63;
    const int w    = __builtin_amdgcn_readfirstlane(tid >> 6);
    const int col  = lane & 31;
    const int sel8 = lane >> 5;
    const int pgrp = blockIdx.x;

    __shared__ char  ebuf[4][8192];   // ring: [buf][eh 4KB | el 4KB] = 32KB
    __shared__ float lds_e2[1024];    // 4KB fp32 ||e||^2, all codes
    __shared__ int   s_final[128];

    // ---- A fragments: a = -2 z[pt], hi/lo fp16 ----
    const int pt = pgrp * 128 + w * 32 + col;
    half8 ah[4], al[4];
    {
        const float* zrow = z + (size_t)pt * DDIM + sel8 * 8;
        #pragma unroll
        for (int ks = 0; ks < 4; ++ks) {
            float4 u0 = *(const float4*)(zrow + ks * 16);
            float4 u1 = *(const float4*)(zrow + ks * 16 + 4);
            float tv[8] = {u0.x, u0.y, u0.z, u0.w, u1.x, u1.y, u1.z, u1.w};
            #pragma unroll
            for (int j = 0; j < 8; ++j) {
                float a = -2.0f * tv[j];
                _Float16 hh = (_Float16)a;
                ah[ks][j] = hh;
                al[ks][j] = (_Float16)(a - (float)hh);
            }
        }
    }
    // drain A-frag vmem so loop vmcnt accounting sees ONLY gl_lds ops
    asm volatile("s_waitcnt vmcnt(0)" ::: "memory");
    __builtin_amdgcn_sched_barrier(0);

    const floatx16 zeroC = {};
    float best[16];
    int   bt[16];
    #pragma unroll
    for (int r = 0; r < 16; ++r) { best[r] = 3.4e38f; bt[r] = 0; }

    // wave w stages 2KB/tile: operand = w>>1 (0=eh,1=el), half = w&1
    const int opnd = w >> 1, hsel = w & 1;
    const char* gsrc = ws_c + (opnd ? WS_ELP : WS_EHP) + hsel * 2048 + lane * 16;
    char* lbase = &ebuf[0][0] + opnd * 4096 + hsel * 2048;

#define STAGE(BUF, T) do {                                                    \
    const char* _s = gsrc + (size_t)(T) * 4096;                               \
    char* _d = lbase + (BUF) * 8192;                                          \
    gl_lds16(_s,        _d);                                                  \
    gl_lds16(_s + 1024, _d + 1024);                                           \
} while (0)

    const int myoff = sel8 * 512 + col * 16;   // chunk-major frag base in tile

#define READF(BUF, T, BH, BL, E2) do {                                        \
    const char* _b = &ebuf[BUF][0] + myoff;                                   \
    _Pragma("unroll")                                                         \
    for (int ks = 0; ks < 4; ++ks) {                                          \
        BH[ks] = *(const half8*)(_b + ks * 1024);                             \
        BL[ks] = *(const half8*)(_b + 4096 + ks * 1024);                      \
    }                                                                         \
    E2 = lds_e2[(T) * 32 + col];                                              \
} while (0)

// FOUR independent 3-deep chains, issued round-robin so consecutive
// instructions are never dependent (fills the ~150cy dep-latency gaps).
#define COMP(T, BH, BL, E2) do {                                              \
    __builtin_amdgcn_s_setprio(1);                                            \
    floatx16 c0 = MFMA(ah[0], BH[0], zeroC);                                  \
    floatx16 c1 = MFMA(ah[3], BH[3], zeroC);                                  \
    floatx16 c2 = MFMA(al[2], BH[2], zeroC);                                  \
    floatx16 c3 = MFMA(ah[1], BL[1], zeroC);                                  \
    c0 = MFMA(ah[1], BH[1], c0);                                              \
    c1 = MFMA(al[0], BH[0], c1);                                              \
    c2 = MFMA(al[3], BH[3], c2);                                              \
    c3 = MFMA(ah[2], BL[2], c3);                                              \
    c0 = MFMA(ah[2], BH[2], c0);                                              \
    c1 = MFMA(al[1], BH[1], c1);                                              \
    c2 = MFMA(ah[0], BL[0], c2);                                              \
    c3 = MFMA(ah[3], BL[3], c3);                                              \
    __builtin_amdgcn_s_setprio(0);                                            \
    _Pragma("unroll")                                                         \
    for (int r = 0; r < 16; ++r) {                                            \
        float d = ((c0[r] + c1[r]) + (c2[r] + c3[r])) + (E2);                 \
        bool c = d < best[r];          /* strict <: earliest tile wins */     \
        best[r] = c ? d   : best[r];                                          \
        bt[r]   = c ? (T) : bt[r];                                            \
    }                                                                         \
} while (0)

// counted wait + collective barrier. lgkmcnt(0): my ds_reads (issued a full
// COMP ago) retired before anyone overwrites that ring slot after the barrier.
#define WAITBAR(N) do {                                                       \
    asm volatile("s_waitcnt vmcnt(" #N ") lgkmcnt(0)" ::: "memory");          \
    __builtin_amdgcn_sched_barrier(0);                                        \
    __builtin_amdgcn_s_barrier();                                             \
    __builtin_amdgcn_sched_barrier(0);                                        \
} while (0)

    // Named regsets A/B (rule #20: no runtime-indexed register arrays).
    half8 bhA[4], blA[4], bhB[4], blB[4];
    float e2A, e2B;

    // -------- prologue: e2 + tiles 0..2 in flight (7 ops) --------
    gl_lds16(ws_c + WS_E2 + w * 1024 + lane * 16, (char*)lds_e2 + w * 1024);
    STAGE(0, 0);
    STAGE(1, 1);
    STAGE(2, 2);
    WAITBAR(4);                 // retire e2 + tile0 (3 oldest ops)
    READF(0, 0, bhA, blA, e2A);
    STAGE(3, 3);                // in flight: tiles 1,2,3 = 6 ops

    // -------- main loop: tiles 0..27, always 3 tiles ahead --------
    #pragma unroll 1
    for (int t = 0; t < 28; t += 2) {
        WAITBAR(4);                              // retire tile t+1
        READF((t + 1) & 3, t + 1, bhB, blB, e2B);
        STAGE((t + 4) & 3, t + 4);
        COMP(t, bhA, blA, e2A);

        WAITBAR(4);                              // retire tile t+2
        READF((t + 2) & 3, t + 2, bhA, blA, e2A);
        STAGE((t + 5) & 3, t + 5);
        COMP(t + 1, bhB, blB, e2B);
    }

    // -------- tail: tiles 28..31, draining the ring --------
    WAITBAR(4);                 // in flight {29,30,31}: retire 29
    READF(29 & 3, 29, bhB, blB, e2B);
    COMP(28, bhA, blA, e2A);

    WAITBAR(2);                 // in flight {30,31}: retire 30
    READF(30 & 3, 30, bhA, blA, e2A);
    COMP(29, bhB, blB, e2B);

    WAITBAR(0);                 // in flight {31}: retire 31
    READF(31 & 3, 31, bhB, blB, e2B);
    COMP(30, bhA, blA, e2A);

    COMP(31, bhB, blB, e2B);
#undef STAGE
#undef READF
#undef COMP
#undef WAITBAR

    // materialize codes; butterfly argmin across the 32 columns
    int code[16];
    #pragma unroll
    for (int r = 0; r < 16; ++r) code[r] = bt[r] * 32 + col;
    #pragma unroll
    for (int m = 1; m < 32; m <<= 1) {
        #pragma unroll
        for (int r = 0; r < 16; ++r) {
            float ov = __shfl_xor(best[r], m, 64);
            int   oc = __shfl_xor(code[r], m, 64);
            bool c = (ov < best[r]) || (ov == best[r] && oc < code[r]);
            best[r] = c ? ov : best[r];
            code[r] = c ? oc : code[r];
        }
    }
    if (col == 0) {   // lanes 0 and 32: 16 rows each
        #pragma unroll
        for (int r = 0; r < 16; ++r) {
            int row = (r & 3) + 8 * (r >> 2) + 4 * sel8;
            s_final[w * 32 + row] = code[r];
        }
    }
    __syncthreads();

    // indices (coalesced) + quantized gather: 128 pts x 16 float4
    if (tid < 128)
        out[QOUT_ELEMS + (size_t)pgrp * 128 + tid] = (float)s_final[tid];
    float4* outq = (float4*)out;
    const float4* emb4 = (const float4*)emb;
    #pragma unroll
    for (int it = 0; it < 8; ++it) {
        int f  = it * 256 + tid;
        int p  = f >> 4;
        int d4 = f & 15;
        int ks = s_final[p];
        outq[((size_t)pgrp * 128 + p) * (DDIM / 4) + d4] =
            emb4[(size_t)ks * (DDIM / 4) + d4];
    }
}

extern "C" void kernel_launch(void* const* d_in, const int* in_sizes, int n_in,
                              void* d_out, int out_size, void* d_ws, size_t ws_size,
                              hipStream_t stream) {
    const float* z   = (const float*)d_in[0];
    const float* emb = (const float*)d_in[1];
    float* out = (float*)d_out;
    char* ws = (char*)d_ws;

    eprep_kernel<<<KCODES / 4, 256, 0, stream>>>(emb, ws);
    vq_kernel<<<NPTS / 128, 256, 0, stream>>>(z, ws, emb, out);
}